// Round 11
// baseline (137.976 us; speedup 1.0000x reference)
//
#include <hip/hip_runtime.h>

// Conv2d 3x3 s1 p1, B=16, CIN=COUT=64, 112x112 — bf16 MFMA implicit-GEMM v4.
// Round-8 thesis: eliminate redundant per-block weight gather.
//  - pack_w pre-kernel: weight f32 [576][64] -> bf16 fragments in d_ws,
//    layout [wv][tap][kc][lane][8] => main kernel B-frag = 1x dwordx4/lane.
//  - x staging as float4 quads (112%4==0): ~10 VMEM/thread (was 21).
//  - global loads issued before the LDS-reuse barrier (issue-early).
// Structure else = v3: 1-row tiles, grid 1792, Mrep=7, LDS [338][40], 4 waves.
// (Resubmission x3 — rounds 8/9/10 broker timeouts; v4 has not yet run.)

#define CIN   64
#define HH    112
#define WW    112
#define COUT  64
#define HW    (HH*WW)      // 12544
#define CHW   (CIN*HW)
#define LDC   40           // padded channel stride (elems) = 80B
#define TROWS 338
#define PKN   (4*9*2*64*8) // 36864 packed bf16 elems

typedef float f32x4 __attribute__((ext_vector_type(4)));
typedef short s16x8 __attribute__((ext_vector_type(8)));
typedef int   s32x4 __attribute__((ext_vector_type(4)));

static __device__ __forceinline__ unsigned short f2bf(float f) {
  unsigned u = __float_as_uint(f);
  u += 0x7fffu + ((u >> 16) & 1u);   // RNE
  return (unsigned short)(u >> 16);
}

// pk[i], i = wv*9216 + tap*1024 + kc*512 + lane*8 + j
//   lane = (col | koct<<4): c = kc*32 + koct*8 + j, co = wv*16 + col
__global__ __launch_bounds__(256) void pack_w_kernel(
    const float* __restrict__ w, unsigned short* __restrict__ pk) {
  const int i = blockIdx.x * 256 + threadIdx.x;
  if (i >= PKN) return;
  const int j    = i & 7;
  const int lane = (i >> 3) & 63;
  const int kc   = (i >> 9) & 1;
  const int tap  = (i >> 10) % 9;
  const int wv   = (i >> 10) / 9;
  const int c  = kc * 32 + (lane >> 4) * 8 + j;
  const int co = wv * 16 + (lane & 15);
  pk[i] = f2bf(w[(c * 9 + tap) * COUT + co]);
}

__global__ __launch_bounds__(256, 4) void conv_mfma_bf16_v4(
    const float* __restrict__ x, const unsigned short* __restrict__ pk,
    const float* __restrict__ bias, float* __restrict__ out) {
  __shared__ __align__(16) unsigned short A[TROWS * LDC];  // 27040 B

  const int tid  = threadIdx.x;
  const int lane = tid & 63;
  const int wv   = tid >> 6;
  const int cobase = wv * 16;
  const int col  = lane & 15;
  const int koct = lane >> 4;

  // XCD swizzle: 1792 = 8 * 224
  const int bx0 = blockIdx.x;
  const int bx  = (bx0 & 7) * 224 + (bx0 >> 3);
  const int b   = bx / 112;
  const int r0  = bx - b * 112;
  const int p0  = r0 * WW;

  const float* xb = x + (size_t)b * CHW;

  const float bv = bias[cobase + col];
  f32x4 acc[7];
#pragma unroll
  for (int m = 0; m < 7; ++m) acc[m] = (f32x4){bv, bv, bv, bv};

  const int stage_base = (r0 - 1) * WW;

#pragma unroll
  for (int kc = 0; kc < 2; ++kc) {
    // ---- B fragments: one coalesced 16B load each (issued early)
    s16x8 bfr[9];
#pragma unroll
    for (int tap = 0; tap < 9; ++tap)
      bfr[tap] = *(const s16x8*)(pk + (size_t)(wv * 9216 + tap * 1024 +
                                              kc * 512 + lane * 8));

    // ---- x staging loads -> regs (before barrier: overlap prev MFMA phase)
    const float* src0 = xb + (size_t)(kc * 32 + wv * 8) * HW;
    f32x4 v[2][8];
    bool act[2];
    int px0v[2];
#pragma unroll
    for (int g = 0; g < 2; ++g) {
      const int pi = lane + 64 * g;           // quad index
      act[g] = pi < 84;                        // 336/4 quads
      const int px0 = 4 * pi;
      px0v[g] = px0;
      const int tr = px0 / WW;                 // tile row 0..2
      const int gr = r0 - 1 + tr;
      const bool val = act[g] && ((unsigned)gr < (unsigned)HH);
      const int goff = val ? (stage_base + px0) : 0;
#pragma unroll
      for (int j = 0; j < 8; ++j)
        v[g][j] = val ? *(const f32x4*)(src0 + (size_t)j * HW + goff)
                      : (f32x4){0.f, 0.f, 0.f, 0.f};
    }

    if (kc) __syncthreads();  // previous phase's A reads complete

    // ---- LDS writes: 4 px per quad, 8ch (16B) each
#pragma unroll
    for (int g = 0; g < 2; ++g) {
      if (act[g]) {
#pragma unroll
        for (int p = 0; p < 4; ++p) {
          unsigned rr[4];
#pragma unroll
          for (int jp = 0; jp < 4; ++jp)
            rr[jp] = (unsigned)f2bf(v[g][2 * jp][p]) |
                     ((unsigned)f2bf(v[g][2 * jp + 1][p]) << 16);
          *(s32x4*)&A[(px0v[g] + p + 1) * LDC + wv * 8] =
              (s32x4){(int)rr[0], (int)rr[1], (int)rr[2], (int)rr[3]};
        }
      }
    }
    __syncthreads();

    // ---- compute: 9 taps x 7 Mfrags, pure LDS->MFMA
#pragma unroll
    for (int tap = 0; tap < 9; ++tap) {
      const int dh = tap / 3 - 1, dw = tap - (tap / 3) * 3 - 1;
      const int tbase = (dh + 1) * WW + dw + 1;
#pragma unroll
      for (int m = 0; m < 7; ++m) {
        s16x8 af = *(const s16x8*)&A[(m * 16 + col + tbase) * LDC + koct * 8];
        if (dw == -1 && m == 0 && col == 0) af = (s16x8){0,0,0,0,0,0,0,0};
        if (dw ==  1 && m == 6 && col == 15) af = (s16x8){0,0,0,0,0,0,0,0};
        acc[m] = __builtin_amdgcn_mfma_f32_16x16x32_bf16(af, bfr[tap],
                                                         acc[m], 0, 0, 0);
      }
    }
  }

  // ---- store
  float* ob = out + (size_t)b * (COUT * HW) + (size_t)(cobase + col) * HW + p0;
#pragma unroll
  for (int m = 0; m < 7; ++m)
    *(f32x4*)(ob + m * 16 + koct * 4) = acc[m];
}

extern "C" void kernel_launch(void* const* d_in, const int* in_sizes, int n_in,
                              void* d_out, int out_size, void* d_ws, size_t ws_size,
                              hipStream_t stream) {
  const float* x = (const float*)d_in[0];
  const float* weight = (const float*)d_in[1];
  const float* bias = (const float*)d_in[2];
  float* out = (float*)d_out;
  unsigned short* pk = (unsigned short*)d_ws;   // 73728 B used

  pack_w_kernel<<<dim3((PKN + 255) / 256), dim3(256), 0, stream>>>(weight, pk);
  conv_mfma_bf16_v4<<<dim3(16 * 112), dim3(256), 0, stream>>>(x, pk, bias, out);
}

// Round 13
// 122.855 us; speedup vs baseline: 1.1231x; 1.1231x over previous
//
#include <hip/hip_runtime.h>

// Conv2d 3x3 s1 p1, B=16, CIN=COUT=64, 112x112 — bf16 MFMA implicit-GEMM v5.
// Round-12 thesis: LDS-read amortization. 2-row tiles (224 px, 14 M-frags),
// 4 waves = 2 co-halves x 2 M-halves; wave M_rep=7, N_rep=2 -> one A-read
// feeds 2 MFMAs (LDS reads/px: 9 -> 2.25). B-frags per-tap from packed pk
// (L2). 2-row writes = 896B = 7 full 128B lines (kills v4's RMW inflation).
// launch_bounds(256,3) so staged loads can stay in flight across barrier.
// (Resubmission — round 12 broker timeout; v5 has not yet run.)

#define CIN   64
#define HH    112
#define WW    112
#define COUT  64
#define HW    (HH*WW)      // 12544
#define CHW   (CIN*HW)
#define LDC   40           // padded channel stride (elems) = 80B
#define TROWS 450          // 448 tile px + edge slots (masked reads)
#define PKN   (4*9*2*64*8) // 36864 packed bf16 elems

typedef float f32x4 __attribute__((ext_vector_type(4)));
typedef short s16x8 __attribute__((ext_vector_type(8)));
typedef int   s32x4 __attribute__((ext_vector_type(4)));

static __device__ __forceinline__ unsigned short f2bf(float f) {
  unsigned u = __float_as_uint(f);
  u += 0x7fffu + ((u >> 16) & 1u);   // RNE
  return (unsigned short)(u >> 16);
}

// pk[i], i = cog*9216 + tap*1024 + kc*512 + lane*8 + j
//   lane = (col | koct<<4): c = kc*32 + koct*8 + j, co = cog*16 + col
__global__ __launch_bounds__(256) void pack_w_kernel(
    const float* __restrict__ w, unsigned short* __restrict__ pk) {
  const int i = blockIdx.x * 256 + threadIdx.x;
  if (i >= PKN) return;
  const int j    = i & 7;
  const int lane = (i >> 3) & 63;
  const int kc   = (i >> 9) & 1;
  const int tap  = (i >> 10) % 9;
  const int cog  = (i >> 10) / 9;
  const int c  = kc * 32 + (lane >> 4) * 8 + j;
  const int co = cog * 16 + (lane & 15);
  pk[i] = f2bf(w[(c * 9 + tap) * COUT + co]);
}

__global__ __launch_bounds__(256, 3) void conv_mfma_bf16_v5(
    const float* __restrict__ x, const unsigned short* __restrict__ pk,
    const float* __restrict__ bias, float* __restrict__ out) {
  __shared__ __align__(16) unsigned short A[TROWS * LDC];  // 36000 B

  const int tid  = threadIdx.x;
  const int lane = tid & 63;
  const int wv   = tid >> 6;        // staging ch-octet
  const int nh   = wv & 1;          // co-half: couts [nh*32, nh*32+32)
  const int mh   = wv >> 1;         // M-half: frags [mh*7, mh*7+7)
  const int col  = lane & 15;
  const int koct = lane >> 4;

  // XCD swizzle: 896 = 8 * 112; consecutive row-pairs share an XCD L2
  const int bx0 = blockIdx.x;
  const int bx  = (bx0 & 7) * 112 + (bx0 >> 3);
  const int b   = bx / 56;
  const int r0  = (bx - b * 56) * 2;   // first output row
  const int p0  = r0 * WW;

  const float* xb = x + (size_t)b * CHW;

  f32x4 acc[7][2];
#pragma unroll
  for (int nf = 0; nf < 2; ++nf) {
    const float bv = bias[(nh * 2 + nf) * 16 + col];
#pragma unroll
    for (int mf = 0; mf < 7; ++mf) acc[mf][nf] = (f32x4){bv, bv, bv, bv};
  }

  const int stage_base = (r0 - 1) * WW;

#pragma unroll
  for (int kc = 0; kc < 2; ++kc) {
    // ---- x staging loads -> regs (issued before the reuse barrier)
    const float* src0 = xb + (size_t)(kc * 32 + wv * 8) * HW;
    f32x4 v[2][8];
    bool act[2];
    int px0v[2];
#pragma unroll
    for (int g = 0; g < 2; ++g) {
      const int pi = lane + 64 * g;            // quad index 0..111
      act[g] = pi < 112;
      const int px0 = 4 * pi;                  // tile px 0..444
      px0v[g] = px0;
      const int tr = px0 / WW;                 // tile row 0..3
      const int gr = r0 - 1 + tr;
      const bool val = act[g] && ((unsigned)gr < (unsigned)HH);
      const int goff = val ? (stage_base + px0) : 0;
#pragma unroll
      for (int j = 0; j < 8; ++j)
        v[g][j] = val ? *(const f32x4*)(src0 + (size_t)j * HW + goff)
                      : (f32x4){0.f, 0.f, 0.f, 0.f};
    }

    if (kc) __syncthreads();  // previous phase's A reads complete

#pragma unroll
    for (int g = 0; g < 2; ++g) {
      if (act[g]) {
#pragma unroll
        for (int p = 0; p < 4; ++p) {
          unsigned rr[4];
#pragma unroll
          for (int jp = 0; jp < 4; ++jp)
            rr[jp] = (unsigned)f2bf(v[g][2 * jp][p]) |
                     ((unsigned)f2bf(v[g][2 * jp + 1][p]) << 16);
          *(s32x4*)&A[(px0v[g] + p + 1) * LDC + wv * 8] =
              (s32x4){(int)rr[0], (int)rr[1], (int)rr[2], (int)rr[3]};
        }
      }
    }
    __syncthreads();

    // ---- compute: 9 taps x (7 A-reads -> 14 MFMAs); B per-tap from pk (L2)
#pragma unroll
    for (int tap = 0; tap < 9; ++tap) {
      const int dh = tap / 3 - 1, dw = tap - (tap / 3) * 3 - 1;
      // output px o = mh*112 + mf*16 + col ; A slot = o + tbase
      const int tbase = mh * 112 + (dh + 1) * WW + dw + 1;
      s16x8 bfr[2];
#pragma unroll
      for (int nf = 0; nf < 2; ++nf)
        bfr[nf] = *(const s16x8*)(pk + (size_t)((nh * 2 + nf) * 9216 +
                                                tap * 1024 + kc * 512 +
                                                lane * 8));
#pragma unroll
      for (int mf = 0; mf < 7; ++mf) {
        s16x8 af = *(const s16x8*)&A[(mf * 16 + col + tbase) * LDC + koct * 8];
        // ow = mf*16+col; dw=-1 invalid at ow==0; dw=+1 invalid at ow==111
        if (dw == -1 && mf == 0 && col == 0) af = (s16x8){0,0,0,0,0,0,0,0};
        if (dw ==  1 && mf == 6 && col == 15) af = (s16x8){0,0,0,0,0,0,0,0};
#pragma unroll
        for (int nf = 0; nf < 2; ++nf)
          acc[mf][nf] = __builtin_amdgcn_mfma_f32_16x16x32_bf16(
              af, bfr[nf], acc[mf][nf], 0, 0, 0);
      }
    }
  }

  // ---- store: plane co = (nh*2+nf)*16+col, px = p0 + mh*112 + mf*16 + koct*4
#pragma unroll
  for (int nf = 0; nf < 2; ++nf) {
    float* ob = out + (size_t)b * (COUT * HW) +
                (size_t)((nh * 2 + nf) * 16 + col) * HW + p0 + mh * 112;
#pragma unroll
    for (int mf = 0; mf < 7; ++mf)
      *(f32x4*)(ob + mf * 16 + koct * 4) = acc[mf][nf];
  }
}

extern "C" void kernel_launch(void* const* d_in, const int* in_sizes, int n_in,
                              void* d_out, int out_size, void* d_ws, size_t ws_size,
                              hipStream_t stream) {
  const float* x = (const float*)d_in[0];
  const float* weight = (const float*)d_in[1];
  const float* bias = (const float*)d_in[2];
  float* out = (float*)d_out;
  unsigned short* pk = (unsigned short*)d_ws;   // 73728 B used

  pack_w_kernel<<<dim3((PKN + 255) / 256), dim3(256), 0, stream>>>(weight, pk);
  conv_mfma_bf16_v5<<<dim3(16 * 56), dim3(256), 0, stream>>>(x, pk, bias, out);
}